// Round 14
// baseline (456.146 us; speedup 1.0000x reference)
//
#include <hip/hip_runtime.h>

// Problem constants (fixed by the reference)
#define N_NODES 20000
#define N_EDGES 320000
#define ETOT    (N_EDGES + N_NODES)   // edges + self-loops = 340000
#define HEADS   10
#define F_IN    32
#define C1      (HEADS * F_IN)        // 320
#define C2      128
#define NB      100
#define PER     200
#define CAP     96                    // CSR bucket capacity (max in-degree << 96)
#define HSTRIDE 328                   // padded tile row stride (ushort)
#define X2STRIDE 136                  // padded x2-tile row stride (f16)

typedef __attribute__((ext_vector_type(8))) short bf16x8;   // MFMA A/B frag (4 VGPRs)
typedef __attribute__((ext_vector_type(4))) float floatx4;  // MFMA C/D frag
typedef _Float16 f16;
typedef _Float16 f16x2 __attribute__((ext_vector_type(2)));
typedef _Float16 f16x8 __attribute__((ext_vector_type(8)));

static __device__ __forceinline__ unsigned short f2bf(float f) {
    unsigned int u = __float_as_uint(f);
    unsigned int r = (u + 0x7fffu + ((u >> 16) & 1u)) >> 16;   // RNE
    return (unsigned short)r;
}

// ---------------------------------------------------------------------------
// Mega prep: CSR scatter + layer-1 scores (local WA fold) + W2/W1/FC B-frag
// prep + feats->f16.  cursor/pooled/done zeroed by a prior hipMemsetAsync.
// ---------------------------------------------------------------------------
#define SCAT_BLOCKS  ((ETOT + 255) / 256)               // 1329
#define SCORE_BLOCKS ((N_NODES + 63) / 64)              // 313
#define W2P_BLOCKS   ((C1 * C2 + 255) / 256)            // 160
#define W1P_BLOCKS   ((HEADS * F_IN * F_IN + 255) / 256)// 40
#define FCP_BLOCKS   ((C2 * C2 + 255) / 256)            // 64
#define F16_BLOCKS   ((N_NODES * F_IN / 4 + 255) / 256) // 625
__global__ __launch_bounds__(256) void mega_prep_kernel(
        const int* __restrict__ ei, int* __restrict__ cursor, int* __restrict__ csr_src,
        const float* __restrict__ feats, f16* __restrict__ feats16,
        const float* __restrict__ W1, unsigned short* __restrict__ W1p,
        const float* __restrict__ W2, unsigned short* __restrict__ W2p,
        const float* __restrict__ fcw, f16* __restrict__ FCp,
        const float* __restrict__ a1s, const float* __restrict__ a1d,
        float* __restrict__ s_src, float* __restrict__ s_dst) {
    unsigned int b = blockIdx.x;
    if (b < SCAT_BLOCKS) {
        int e = b * 256 + threadIdx.x;
        if (e >= ETOT) return;
        int s, d;
        if (e < N_EDGES) { s = ei[e]; d = ei[N_EDGES + e]; }
        else             { s = e - N_EDGES; d = s; }
        int pos = atomicAdd(&cursor[d], 1);
        csr_src[(size_t)d * CAP + pos] = s;
        return;
    }
    b -= SCAT_BLOCKS;
    if (b < SCORE_BLOCKS) {
        __shared__ __align__(16) float A[64 * F_IN];   // 8 KB
        __shared__ float Ws[C1], Wd[C1];
        int t = threadIdx.x;
        // fold attention vectors through W1 locally: Ws[k*10+h] = sum_f W1[k][h*32+f]*a1s[h*32+f]
        for (int o = t; o < C1; o += 256) {
            int k = o & 31, h = o >> 5;
            float ss = 0.f, dd = 0.f;
#pragma unroll
            for (int f = 0; f < F_IN; f++) {
                float wv = W1[k * C1 + h * 32 + f];
                ss += wv * a1s[h * 32 + f];
                dd += wv * a1d[h * 32 + f];
            }
            Ws[k * HEADS + h] = ss;
            Wd[k * HEADS + h] = dd;
        }
        int n0 = b * 64;
        int nrows = min(64, N_NODES - n0);
        const float4* fs = (const float4*)(feats + (size_t)n0 * F_IN);
        float4* Af = (float4*)A;
        for (int i = t; i < nrows * 8; i += 256) Af[i] = fs[i];
        __syncthreads();
        for (int o = t; o < nrows * HEADS; o += 256) {
            int nl = o / HEADS, h = o - nl * HEADS;
            const float* ar = A + nl * F_IN;
            float ss = 0.f, dd = 0.f;
#pragma unroll
            for (int k = 0; k < F_IN; k++) {
                float av = ar[k];
                ss += av * Ws[k * HEADS + h];
                dd += av * Wd[k * HEADS + h];
            }
            s_src[(size_t)(n0 + nl) * HEADS + h] = ss;
            s_dst[(size_t)(n0 + nl) * HEADS + h] = dd;
        }
        return;
    }
    b -= SCORE_BLOCKS;
    if (b < W2P_BLOCKS) {
        int o = b * 256 + threadIdx.x;   // 40960
        if (o >= C1 * C2) return;
        int j    = o & 7;
        int lane = (o >> 3) & 63;
        int ct   = (o >> 9) & 7;
        int kb   = o >> 12;
        int k = kb * 32 + (lane >> 4) * 8 + j;
        int n = ct * 16 + (lane & 15);
        W2p[o] = f2bf(W2[k * C2 + n]);
        return;
    }
    b -= W2P_BLOCKS;
    if (b < W1P_BLOCKS) {
        int o = b * 256 + threadIdx.x;   // 10240
        if (o >= HEADS * F_IN * F_IN) return;
        int j    = o & 7;
        int lane = (o >> 3) & 63;
        int ct   = (o >> 9) & 1;
        int h    = o >> 10;
        int k = (lane >> 4) * 8 + j;
        int f = ct * 16 + (lane & 15);
        W1p[o] = f2bf(W1[k * C1 + h * 32 + f]);
        return;
    }
    b -= W1P_BLOCKS;
    if (b < FCP_BLOCKS) {
        int o = b * 256 + threadIdx.x;   // 16384
        if (o >= C2 * C2) return;
        int j    = o & 7;
        int lane = (o >> 3) & 63;
        int ct   = (o >> 9) & 7;
        int kb   = o >> 12;
        int k = kb * 32 + (lane >> 4) * 8 + j;
        int n = ct * 16 + (lane & 15);
        FCp[o] = (f16)fcw[k * C2 + n];
        return;
    }
    b -= FCP_BLOCKS;
    {
        int o = b * 256 + threadIdx.x;
        if (o < N_NODES * F_IN / 4) {
            float4 v = ((const float4*)feats)[o];
            f16* d = feats16 + 4 * o;
            d[0] = (f16)v.x; d[1] = (f16)v.y; d[2] = (f16)v.z; d[3] = (f16)v.w;
        }
    }
}

// ---------------------------------------------------------------------------
// Layer-1 gather: gn[n,h,k] = (sum_e p_eh * feats[s_e,k]) / l_h   (bf16 out)
// ONE WAVE per node (20000 independent waves — degree tail averages out).
// ---------------------------------------------------------------------------
__global__ __launch_bounds__(256) void aggg1_kernel(
        const f16* __restrict__ feats16, const float* __restrict__ s_src,
        const float* __restrict__ s_dst, const int* __restrict__ deg_arr,
        const int* __restrict__ csr_src, unsigned short* __restrict__ gn) {
    __shared__ __align__(4) f16 shP[4][HEADS * 64];
    __shared__ __align__(8) int shS[4][64];
    int wslot = threadIdx.x >> 6;
    int n = blockIdx.x * 4 + wslot;                   // 20000 waves, 1 node each
    int lane = threadIdx.x & 63;
    int k = lane & 31, half = lane >> 5;
    f16* P = shP[wslot];
    int* S = shS[wslot];
    const f16x2 ones = {(f16)1.f, (f16)1.f};

    int beg = n * CAP, deg = deg_arr[n];
    const float* sdp = s_dst + (size_t)n * HEADS;
    float sd[10];
#pragma unroll
    for (int q = 0; q < 5; q++) {
        float2 v = *(const float2*)(sdp + 2 * q);
        sd[2 * q] = v.x; sd[2 * q + 1] = v.y;
    }
    float g[10], la[10];
#pragma unroll
    for (int h = 0; h < 10; h++) { g[h] = 0.f; la[h] = 0.f; }

    for (int c0 = 0; c0 < deg; c0 += 64) {
        int dc = min(deg - c0, 64);
        bool act = lane < dc;
        int s_e = csr_src[beg + c0 + min(lane, dc - 1)];
        const float* ssp = s_src + (size_t)s_e * HEADS;
        float p[10];
#pragma unroll
        for (int q = 0; q < 5; q++) {
            float2 v = *(const float2*)(ssp + 2 * q);
            float e0 = v.x + sd[2 * q];
            float e1 = v.y + sd[2 * q + 1];
            e0 = (e0 >= 0.f) ? e0 : 0.2f * e0;   // leaky_relu(0.2)
            e1 = (e1 >= 0.f) ? e1 : 0.2f * e1;
            p[2 * q]     = act ? __expf(e0) : 0.f;
            p[2 * q + 1] = act ? __expf(e1) : 0.f;
        }
        S[lane] = s_e;
#pragma unroll
        for (int h = 0; h < 10; h++) P[h * 64 + lane] = (f16)p[h];
        asm volatile("s_waitcnt lgkmcnt(0)" ::: "memory");

        int dcp = (dc + 3) & ~3;
        for (int i = 0; i < dcp; i += 4) {
            int e0 = i + half * 2;               // this half's edge pair
            int2 ss2 = *(const int2*)&S[e0];
            f16x2 v;
            v.x = feats16[(size_t)ss2.x * F_IN + k];
            v.y = feats16[(size_t)ss2.y * F_IN + k];
#pragma unroll
            for (int h = 0; h < 10; h++) {
                f16x2 pp = *(const f16x2*)&P[h * 64 + e0];
                g[h]  = __builtin_amdgcn_fdot2(pp, v, g[h], false);
                la[h] = __builtin_amdgcn_fdot2(pp, ones, la[h], false);
            }
        }
        asm volatile("s_waitcnt lgkmcnt(0)" ::: "memory");
    }
#pragma unroll
    for (int h = 0; h < 10; h++) {
        g[h]  += __shfl_xor(g[h], 32);
        la[h] += __shfl_xor(la[h], 32);
    }
    if (half == 0) {
        unsigned short* gp = gn + (size_t)n * C1 + k;
#pragma unroll
        for (int h = 0; h < 10; h++)
            gp[h * 32] = f2bf(g[h] / fmaxf(la[h], 1e-16f));
    }
}

// ---------------------------------------------------------------------------
// Fused h1 + gemm2: per 16-row tile (2 waves/tile, 2 tiles/block)
// ---------------------------------------------------------------------------
__global__ __launch_bounds__(256) void h1gemm2_kernel(
        const unsigned short* __restrict__ gn, const unsigned short* __restrict__ W1p,
        const float* __restrict__ b1, const unsigned short* __restrict__ W2p,
        const float* __restrict__ a_src, const float* __restrict__ a_dst,
        f16* __restrict__ xw2h, float* __restrict__ s_src2, float* __restrict__ s_dst2) {
    __shared__ unsigned short H[2][16 * HSTRIDE];   // 21 KB
    __shared__ float redS[2][2][16], redD[2][2][16];
    int waveId = threadIdx.x >> 6;
    int tl = waveId >> 1;
    int w  = waveId & 1;
    int tile = blockIdx.x * 2 + tl;      // 625 blocks x 2 = 1250 tiles
    int lane = threadIdx.x & 63;
    int quad = lane >> 4, col = lane & 15;
    int row0 = tile * 16;

#pragma unroll
    for (int hh = 0; hh < 5; hh++) {
        int h = w * 5 + hh;
        bf16x8 a = *(const bf16x8*)(gn + (size_t)(row0 + col) * C1 + h * 32 + quad * 8);
        bf16x8 bA = ((const bf16x8*)W1p)[(h * 2 + 0) * 64 + lane];
        bf16x8 bB = ((const bf16x8*)W1p)[(h * 2 + 1) * 64 + lane];
        floatx4 z = {0.f, 0.f, 0.f, 0.f};
        floatx4 c0 = __builtin_amdgcn_mfma_f32_16x16x32_bf16(a, bA, z, 0, 0, 0);
        floatx4 c1 = __builtin_amdgcn_mfma_f32_16x16x32_bf16(a, bB, z, 0, 0, 0);
        float bias0 = b1[h * 32 + col];
        float bias1 = b1[h * 32 + 16 + col];
#pragma unroll
        for (int reg = 0; reg < 4; reg++) {
            int r = quad * 4 + reg;
            float o0 = c0[reg] + bias0;
            float o1 = c1[reg] + bias1;
            o0 = (o0 > 0.f) ? o0 : (__expf(o0) - 1.f);
            o1 = (o1 > 0.f) ? o1 : (__expf(o1) - 1.f);
            H[tl][r * HSTRIDE + h * 32 + col]      = f2bf(o0);
            H[tl][r * HSTRIDE + h * 32 + 16 + col] = f2bf(o1);
        }
    }
    __syncthreads();

    floatx4 acc[4];
#pragma unroll
    for (int c = 0; c < 4; c++) acc[c] = (floatx4){0.f, 0.f, 0.f, 0.f};
    const bf16x8* pb = (const bf16x8*)W2p;
#pragma unroll
    for (int kb = 0; kb < 10; kb++) {
        bf16x8 a = *(const bf16x8*)&H[tl][(lane & 15) * HSTRIDE + kb * 32 + quad * 8];
#pragma unroll
        for (int c = 0; c < 4; c++) {
            bf16x8 b = pb[(kb * 8 + (4 * w + c)) * 64 + lane];
            acc[c] = __builtin_amdgcn_mfma_f32_16x16x32_bf16(a, b, acc[c], 0, 0, 0);
        }
    }
    float asv[4], adv[4];
#pragma unroll
    for (int c = 0; c < 4; c++) {
        asv[c] = a_src[(4 * w + c) * 16 + col];
        adv[c] = a_dst[(4 * w + c) * 16 + col];
    }
#pragma unroll
    for (int reg = 0; reg < 4; reg++) {
        int row = row0 + quad * 4 + reg;
        float vs = 0.f, vd = 0.f;
#pragma unroll
        for (int c = 0; c < 4; c++) {
            float v = acc[c][reg];
            xw2h[(size_t)row * C2 + (4 * w + c) * 16 + col] = (f16)v;
            vs += v * asv[c];
            vd += v * adv[c];
        }
#pragma unroll
        for (int off = 8; off >= 1; off >>= 1) {
            vs += __shfl_xor(vs, off);
            vd += __shfl_xor(vd, off);
        }
        if (col == 0) { redS[tl][w][quad * 4 + reg] = vs; redD[tl][w][quad * 4 + reg] = vd; }
    }
    __syncthreads();
    if (w == 0) {
        if (lane < 16)
            s_src2[row0 + lane] = redS[tl][0][lane] + redS[tl][1][lane];
        else if (lane < 32)
            s_dst2[row0 + lane - 16] = redD[tl][0][lane - 16] + redD[tl][1][lane - 16];
    }
}

// ---------------------------------------------------------------------------
// Fused layer-2 aggregation + fc (+ last-block pooled fc): one 16-node tile,
// 256 threads, 4 nodes/wave.
// ---------------------------------------------------------------------------
__global__ __launch_bounds__(256) void agg2fc_kernel(
        const f16* __restrict__ xw2h, const float* __restrict__ s_src2,
        const float* __restrict__ s_dst2, const int* __restrict__ deg_arr,
        const int* __restrict__ csr_src, const float* __restrict__ b2,
        const f16* __restrict__ FCp, const float* __restrict__ fcw,
        const float* __restrict__ fcb, float* __restrict__ out,
        int* __restrict__ pooledi, int* __restrict__ donecnt,
        float* __restrict__ outp) {
    __shared__ __align__(8) int2 shE[4][64];          // 2 KB
    __shared__ __align__(16) f16 X[16 * X2STRIDE];    // 4.25 KB
    __shared__ float mx[C2];
    __shared__ int isLast;
    int wslot = threadIdx.x >> 6;
    int lane = threadIdx.x & 63;
    int row0 = blockIdx.x * 16;          // 1250 blocks
    int2* E = shE[wslot];

    // ---- phase 1: 4 nodes per wave ----
#pragma unroll
    for (int rep = 0; rep < 4; rep++) {
        int r = wslot * 4 + rep;
        int n = row0 + r;
        int beg = n * CAP, deg = deg_arr[n];
        float sd = s_dst2[n];
        float l = 0.f, a0 = 0.f, a1 = 0.f;

        for (int c0 = 0; c0 < deg; c0 += 64) {
            int dc = min(deg - c0, 64);
            bool act = lane < dc;
            int s_e = csr_src[beg + c0 + min(lane, dc - 1)];
            float e = s_src2[s_e] + sd;
            e = (e >= 0.f) ? e : 0.2f * e;
            float p = act ? __expf(e) : 0.f;
            float su = p;
#pragma unroll
            for (int off = 32; off >= 1; off >>= 1) su += __shfl_xor(su, off);
            l += su;

            E[lane] = make_int2(s_e, __float_as_int(p));
            asm volatile("s_waitcnt lgkmcnt(0)" ::: "memory");

            int dcr = (dc + 3) & ~3;                  // pad rows have p=0
            for (int i = 0; i < dcr; i += 4) {
                int2 e0 = E[i + 0], e1 = E[i + 1], e2 = E[i + 2], e3 = E[i + 3];
                f16x2 v0 = *(const f16x2*)(xw2h + (size_t)e0.x * C2 + 2 * lane);
                f16x2 v1 = *(const f16x2*)(xw2h + (size_t)e1.x * C2 + 2 * lane);
                f16x2 v2 = *(const f16x2*)(xw2h + (size_t)e2.x * C2 + 2 * lane);
                f16x2 v3 = *(const f16x2*)(xw2h + (size_t)e3.x * C2 + 2 * lane);
                float p0 = __int_as_float(e0.y), p1 = __int_as_float(e1.y);
                float p2 = __int_as_float(e2.y), p3 = __int_as_float(e3.y);
                a0 += p0 * (float)v0.x + p1 * (float)v1.x + p2 * (float)v2.x + p3 * (float)v3.x;
                a1 += p0 * (float)v0.y + p1 * (float)v1.y + p2 * (float)v2.y + p3 * (float)v3.y;
            }
            asm volatile("s_waitcnt lgkmcnt(0)" ::: "memory");
        }

        float linv = 1.f / fmaxf(l, 1e-16f);
        float2 bb = *(const float2*)(b2 + 2 * lane);
        f16x2 o;
        o.x = (f16)fmaxf(a0 * linv + bb.x, 0.f);
        o.y = (f16)fmaxf(a1 * linv + bb.y, 0.f);
        *(f16x2*)&X[r * X2STRIDE + 2 * lane] = o;
    }
    __syncthreads();

    // ---- phase 2a: fc MFMA — wave w covers ct = 2w, 2w+1 ----
    int quad = lane >> 4, col = lane & 15;
    floatx4 acc[2];
    acc[0] = (floatx4){0.f, 0.f, 0.f, 0.f};
    acc[1] = (floatx4){0.f, 0.f, 0.f, 0.f};
    const f16x8* pb = (const f16x8*)FCp;
#pragma unroll
    for (int kb = 0; kb < 4; kb++) {
        f16x8 a = *(const f16x8*)&X[(lane & 15) * X2STRIDE + kb * 32 + quad * 8];
#pragma unroll
        for (int c = 0; c < 2; c++) {
            int ct = wslot * 2 + c;
            f16x8 b = pb[(kb * 8 + ct) * 64 + lane];
            acc[c] = __builtin_amdgcn_mfma_f32_16x16x32_f16(a, b, acc[c], 0, 0, 0);
        }
    }
#pragma unroll
    for (int c = 0; c < 2; c++) {
        int ct = wslot * 2 + c;
        float bias = fcb[ct * 16 + col];
#pragma unroll
        for (int reg = 0; reg < 4; reg++) {
            int row = row0 + quad * 4 + reg;
            out[(size_t)row * C2 + ct * 16 + col] = fmaxf(acc[c][reg] + bias, 0.f);
        }
    }

    // ---- phase 2b: tile-local pooling max + atomicMax (threads 0..127) ----
    if (threadIdx.x < C2) {
        int c = threadIdx.x;
        int gA = row0 / PER;
        int gB = (row0 + 15) / PER;
        float mA = 0.f, mB = 0.f;        // x2 >= 0, 0 is identity
#pragma unroll
        for (int r = 0; r < 16; r++) {
            float v = (float)X[r * X2STRIDE + c];
            if ((row0 + r) / PER == gA) mA = fmaxf(mA, v);
            else                        mB = fmaxf(mB, v);
        }
        atomicMax(&pooledi[gA * C2 + c], __float_as_int(mA));
        if (gB != gA) atomicMax(&pooledi[gB * C2 + c], __float_as_int(mB));
    }

    // ---- phase 3: last block computes pooled fc ----
    __threadfence();
    if (threadIdx.x == 0) {
        int v = atomicAdd(donecnt, 1);
        isLast = (v == (int)gridDim.x - 1);
    }
    __syncthreads();
    if (!isLast) return;
    for (int g = 0; g < NB; g++) {
        if (threadIdx.x < C2)   // device-scope read via atomic (cross-XCD safe)
            mx[threadIdx.x] = __int_as_float(atomicAdd(&pooledi[g * C2 + threadIdx.x], 0));
        __syncthreads();
        if (threadIdx.x < C2) {
            int t = threadIdx.x;
            float acc2 = 0.f;
            for (int k = 0; k < C2; k++) acc2 += mx[k] * fcw[k * C2 + t];
            outp[g * C2 + t] = fmaxf(acc2 + fcb[t], 0.f);
        }
        __syncthreads();
    }
}

// ---------------------------------------------------------------------------
extern "C" void kernel_launch(void* const* d_in, const int* in_sizes, int n_in,
                              void* d_out, int out_size, void* d_ws, size_t ws_size,
                              hipStream_t stream) {
    const float* feats = (const float*)d_in[0];
    const int*   ei    = (const int*)d_in[1];
    const float* W1  = (const float*)d_in[4];
    const float* a1s = (const float*)d_in[5];
    const float* a1d = (const float*)d_in[6];
    const float* b1  = (const float*)d_in[7];
    const float* W2  = (const float*)d_in[8];
    const float* a2s = (const float*)d_in[9];
    const float* a2d = (const float*)d_in[10];
    const float* b2  = (const float*)d_in[11];
    const float* fcw = (const float*)d_in[12];
    const float* fcb = (const float*)d_in[13];

    float* out_main = (float*)d_out;                        // [20000,128]
    float* out_pool = (float*)d_out + (size_t)N_NODES * C2; // [100,128]

    char* p = (char*)d_ws;
    auto alloc = [&](size_t bytes) {
        char* r = p;
        p += (bytes + 255) & ~(size_t)255;
        return r;
    };
    unsigned short* gn   = (unsigned short*)alloc(sizeof(short) * (size_t)N_NODES * C1);
    unsigned short* W2p  = (unsigned short*)alloc(sizeof(short) * C1 * C2);
    unsigned short* W1p  = (unsigned short*)alloc(sizeof(short) * HEADS * F_IN * F_IN);
    f16*   FCp     = (f16*)alloc(sizeof(f16) * C2 * C2);
    f16*   feats16 = (f16*)alloc(sizeof(f16) * (size_t)N_NODES * F_IN);
    f16*   xw2h    = (f16*)alloc(sizeof(f16) * (size_t)N_NODES * C2);
    float* s1s    = (float*)alloc(sizeof(float) * N_NODES * HEADS);
    float* s1d    = (float*)alloc(sizeof(float) * N_NODES * HEADS);
    float* s2s    = (float*)alloc(sizeof(float) * N_NODES);
    float* s2d    = (float*)alloc(sizeof(float) * N_NODES);
    // zero region: cursor + pooledi + donecnt in one memset
    const int NZ = N_NODES + NB * C2 + 64;
    int* zeros   = (int*)alloc(sizeof(int) * NZ);
    int* cursor  = zeros;
    int* pooledi = zeros + N_NODES;
    int* donecnt = zeros + N_NODES + NB * C2;
    int* csr_src = (int*)alloc(sizeof(int) * N_NODES * CAP); // bucket CSR

    hipMemsetAsync(zeros, 0, sizeof(int) * NZ, stream);

    mega_prep_kernel<<<SCAT_BLOCKS + SCORE_BLOCKS + W2P_BLOCKS + W1P_BLOCKS + FCP_BLOCKS + F16_BLOCKS,
                       256, 0, stream>>>(
        ei, cursor, csr_src, feats, feats16, W1, W1p, W2, W2p, fcw, FCp,
        a1s, a1d, s1s, s1d);

    aggg1_kernel<<<5000, 256, 0, stream>>>(feats16, s1s, s1d, cursor, csr_src, gn);
    h1gemm2_kernel<<<625, 256, 0, stream>>>(gn, W1p, b1, W2p, a2s, a2d, xw2h, s2s, s2d);
    agg2fc_kernel<<<1250, 256, 0, stream>>>(xw2h, s2s, s2d, cursor, csr_src, b2,
                                            FCp, fcw, fcb, out_main, pooledi, donecnt, out_pool);
}

// Round 15
// 166.113 us; speedup vs baseline: 2.7460x; 2.7460x over previous
//
#include <hip/hip_runtime.h>

// Problem constants (fixed by the reference)
#define N_NODES 20000
#define N_EDGES 320000
#define ETOT    (N_EDGES + N_NODES)   // edges + self-loops = 340000
#define HEADS   10
#define F_IN    32
#define C1      (HEADS * F_IN)        // 320
#define C2      128
#define NB      100
#define PER     200
#define CAP     96                    // CSR bucket capacity (max in-degree << 96)
#define HSTRIDE 328                   // padded tile row stride (ushort)
#define X2STRIDE 136                  // padded x2-tile row stride (f16)

typedef __attribute__((ext_vector_type(8))) short bf16x8;   // MFMA A/B frag (4 VGPRs)
typedef __attribute__((ext_vector_type(4))) float floatx4;  // MFMA C/D frag
typedef _Float16 f16;
typedef _Float16 f16x2 __attribute__((ext_vector_type(2)));
typedef _Float16 f16x8 __attribute__((ext_vector_type(8)));

static __device__ __forceinline__ unsigned short f2bf(float f) {
    unsigned int u = __float_as_uint(f);
    unsigned int r = (u + 0x7fffu + ((u >> 16) & 1u)) >> 16;   // RNE
    return (unsigned short)r;
}

// ---------------------------------------------------------------------------
// Mega prep: CSR scatter + layer-1 scores (local WA fold) + W2/W1/FC B-frag
// prep + feats->f16.  cursor/pooled zeroed by a prior hipMemsetAsync.
// All branches are independent work — no tail serialization.
// ---------------------------------------------------------------------------
#define SCAT_BLOCKS  ((ETOT + 255) / 256)               // 1329
#define SCORE_BLOCKS ((N_NODES + 63) / 64)              // 313
#define W2P_BLOCKS   ((C1 * C2 + 255) / 256)            // 160
#define W1P_BLOCKS   ((HEADS * F_IN * F_IN + 255) / 256)// 40
#define FCP_BLOCKS   ((C2 * C2 + 255) / 256)            // 64
#define F16_BLOCKS   ((N_NODES * F_IN / 4 + 255) / 256) // 625
__global__ __launch_bounds__(256) void mega_prep_kernel(
        const int* __restrict__ ei, int* __restrict__ cursor, int* __restrict__ csr_src,
        const float* __restrict__ feats, f16* __restrict__ feats16,
        const float* __restrict__ W1, unsigned short* __restrict__ W1p,
        const float* __restrict__ W2, unsigned short* __restrict__ W2p,
        const float* __restrict__ fcw, f16* __restrict__ FCp,
        const float* __restrict__ a1s, const float* __restrict__ a1d,
        float* __restrict__ s_src, float* __restrict__ s_dst) {
    unsigned int b = blockIdx.x;
    if (b < SCAT_BLOCKS) {
        int e = b * 256 + threadIdx.x;
        if (e >= ETOT) return;
        int s, d;
        if (e < N_EDGES) { s = ei[e]; d = ei[N_EDGES + e]; }
        else             { s = e - N_EDGES; d = s; }
        int pos = atomicAdd(&cursor[d], 1);
        csr_src[(size_t)d * CAP + pos] = s;
        return;
    }
    b -= SCAT_BLOCKS;
    if (b < SCORE_BLOCKS) {
        __shared__ __align__(16) float A[64 * F_IN];   // 8 KB
        __shared__ float Ws[C1], Wd[C1];
        int t = threadIdx.x;
        // fold attention vectors through W1 locally
        for (int o = t; o < C1; o += 256) {
            int k = o & 31, h = o >> 5;
            float ss = 0.f, dd = 0.f;
#pragma unroll
            for (int f = 0; f < F_IN; f++) {
                float wv = W1[k * C1 + h * 32 + f];
                ss += wv * a1s[h * 32 + f];
                dd += wv * a1d[h * 32 + f];
            }
            Ws[k * HEADS + h] = ss;
            Wd[k * HEADS + h] = dd;
        }
        int n0 = b * 64;
        int nrows = min(64, N_NODES - n0);
        const float4* fs = (const float4*)(feats + (size_t)n0 * F_IN);
        float4* Af = (float4*)A;
        for (int i = t; i < nrows * 8; i += 256) Af[i] = fs[i];
        __syncthreads();
        for (int o = t; o < nrows * HEADS; o += 256) {
            int nl = o / HEADS, h = o - nl * HEADS;
            const float* ar = A + nl * F_IN;
            float ss = 0.f, dd = 0.f;
#pragma unroll
            for (int k = 0; k < F_IN; k++) {
                float av = ar[k];
                ss += av * Ws[k * HEADS + h];
                dd += av * Wd[k * HEADS + h];
            }
            s_src[(size_t)(n0 + nl) * HEADS + h] = ss;
            s_dst[(size_t)(n0 + nl) * HEADS + h] = dd;
        }
        return;
    }
    b -= SCORE_BLOCKS;
    if (b < W2P_BLOCKS) {
        int o = b * 256 + threadIdx.x;   // 40960
        if (o >= C1 * C2) return;
        int j    = o & 7;
        int lane = (o >> 3) & 63;
        int ct   = (o >> 9) & 7;
        int kb   = o >> 12;
        int k = kb * 32 + (lane >> 4) * 8 + j;
        int n = ct * 16 + (lane & 15);
        W2p[o] = f2bf(W2[k * C2 + n]);
        return;
    }
    b -= W2P_BLOCKS;
    if (b < W1P_BLOCKS) {
        int o = b * 256 + threadIdx.x;   // 10240
        if (o >= HEADS * F_IN * F_IN) return;
        int j    = o & 7;
        int lane = (o >> 3) & 63;
        int ct   = (o >> 9) & 1;
        int h    = o >> 10;
        int k = (lane >> 4) * 8 + j;
        int f = ct * 16 + (lane & 15);
        W1p[o] = f2bf(W1[k * C1 + h * 32 + f]);
        return;
    }
    b -= W1P_BLOCKS;
    if (b < FCP_BLOCKS) {
        int o = b * 256 + threadIdx.x;   // 16384
        if (o >= C2 * C2) return;
        int j    = o & 7;
        int lane = (o >> 3) & 63;
        int ct   = (o >> 9) & 7;
        int kb   = o >> 12;
        int k = kb * 32 + (lane >> 4) * 8 + j;
        int n = ct * 16 + (lane & 15);
        FCp[o] = (f16)fcw[k * C2 + n];
        return;
    }
    b -= FCP_BLOCKS;
    {
        int o = b * 256 + threadIdx.x;
        if (o < N_NODES * F_IN / 4) {
            float4 v = ((const float4*)feats)[o];
            f16* d = feats16 + 4 * o;
            d[0] = (f16)v.x; d[1] = (f16)v.y; d[2] = (f16)v.z; d[3] = (f16)v.w;
        }
    }
}

// ---------------------------------------------------------------------------
// Layer-1 gather: gn[n,h,k] = (sum_e p_eh * feats[s_e,k]) / l_h   (bf16 out)
// ONE WAVE per node (20000 independent waves — degree tail averages out).
// ---------------------------------------------------------------------------
__global__ __launch_bounds__(256) void aggg1_kernel(
        const f16* __restrict__ feats16, const float* __restrict__ s_src,
        const float* __restrict__ s_dst, const int* __restrict__ deg_arr,
        const int* __restrict__ csr_src, unsigned short* __restrict__ gn) {
    __shared__ __align__(4) f16 shP[4][HEADS * 64];
    __shared__ __align__(8) int shS[4][64];
    int wslot = threadIdx.x >> 6;
    int n = blockIdx.x * 4 + wslot;                   // 20000 waves, 1 node each
    int lane = threadIdx.x & 63;
    int k = lane & 31, half = lane >> 5;
    f16* P = shP[wslot];
    int* S = shS[wslot];
    const f16x2 ones = {(f16)1.f, (f16)1.f};

    int beg = n * CAP, deg = deg_arr[n];
    const float* sdp = s_dst + (size_t)n * HEADS;
    float sd[10];
#pragma unroll
    for (int q = 0; q < 5; q++) {
        float2 v = *(const float2*)(sdp + 2 * q);
        sd[2 * q] = v.x; sd[2 * q + 1] = v.y;
    }
    float g[10], la[10];
#pragma unroll
    for (int h = 0; h < 10; h++) { g[h] = 0.f; la[h] = 0.f; }

    for (int c0 = 0; c0 < deg; c0 += 64) {
        int dc = min(deg - c0, 64);
        bool act = lane < dc;
        int s_e = csr_src[beg + c0 + min(lane, dc - 1)];
        const float* ssp = s_src + (size_t)s_e * HEADS;
        float p[10];
#pragma unroll
        for (int q = 0; q < 5; q++) {
            float2 v = *(const float2*)(ssp + 2 * q);
            float e0 = v.x + sd[2 * q];
            float e1 = v.y + sd[2 * q + 1];
            e0 = (e0 >= 0.f) ? e0 : 0.2f * e0;   // leaky_relu(0.2)
            e1 = (e1 >= 0.f) ? e1 : 0.2f * e1;
            p[2 * q]     = act ? __expf(e0) : 0.f;
            p[2 * q + 1] = act ? __expf(e1) : 0.f;
        }
        S[lane] = s_e;
#pragma unroll
        for (int h = 0; h < 10; h++) P[h * 64 + lane] = (f16)p[h];
        asm volatile("s_waitcnt lgkmcnt(0)" ::: "memory");

        int dcp = (dc + 3) & ~3;
        for (int i = 0; i < dcp; i += 4) {
            int e0 = i + half * 2;               // this half's edge pair
            int2 ss2 = *(const int2*)&S[e0];
            f16x2 v;
            v.x = feats16[(size_t)ss2.x * F_IN + k];
            v.y = feats16[(size_t)ss2.y * F_IN + k];
#pragma unroll
            for (int h = 0; h < 10; h++) {
                f16x2 pp = *(const f16x2*)&P[h * 64 + e0];
                g[h]  = __builtin_amdgcn_fdot2(pp, v, g[h], false);
                la[h] = __builtin_amdgcn_fdot2(pp, ones, la[h], false);
            }
        }
        asm volatile("s_waitcnt lgkmcnt(0)" ::: "memory");
    }
#pragma unroll
    for (int h = 0; h < 10; h++) {
        g[h]  += __shfl_xor(g[h], 32);
        la[h] += __shfl_xor(la[h], 32);
    }
    if (half == 0) {
        unsigned short* gp = gn + (size_t)n * C1 + k;
#pragma unroll
        for (int h = 0; h < 10; h++)
            gp[h * 32] = f2bf(g[h] / fmaxf(la[h], 1e-16f));
    }
}

// ---------------------------------------------------------------------------
// Fused h1 + gemm2: per 16-row tile (2 waves/tile, 2 tiles/block)
// ---------------------------------------------------------------------------
__global__ __launch_bounds__(256) void h1gemm2_kernel(
        const unsigned short* __restrict__ gn, const unsigned short* __restrict__ W1p,
        const float* __restrict__ b1, const unsigned short* __restrict__ W2p,
        const float* __restrict__ a_src, const float* __restrict__ a_dst,
        f16* __restrict__ xw2h, float* __restrict__ s_src2, float* __restrict__ s_dst2) {
    __shared__ unsigned short H[2][16 * HSTRIDE];   // 21 KB
    __shared__ float redS[2][2][16], redD[2][2][16];
    int waveId = threadIdx.x >> 6;
    int tl = waveId >> 1;
    int w  = waveId & 1;
    int tile = blockIdx.x * 2 + tl;      // 625 blocks x 2 = 1250 tiles
    int lane = threadIdx.x & 63;
    int quad = lane >> 4, col = lane & 15;
    int row0 = tile * 16;

#pragma unroll
    for (int hh = 0; hh < 5; hh++) {
        int h = w * 5 + hh;
        bf16x8 a = *(const bf16x8*)(gn + (size_t)(row0 + col) * C1 + h * 32 + quad * 8);
        bf16x8 bA = ((const bf16x8*)W1p)[(h * 2 + 0) * 64 + lane];
        bf16x8 bB = ((const bf16x8*)W1p)[(h * 2 + 1) * 64 + lane];
        floatx4 z = {0.f, 0.f, 0.f, 0.f};
        floatx4 c0 = __builtin_amdgcn_mfma_f32_16x16x32_bf16(a, bA, z, 0, 0, 0);
        floatx4 c1 = __builtin_amdgcn_mfma_f32_16x16x32_bf16(a, bB, z, 0, 0, 0);
        float bias0 = b1[h * 32 + col];
        float bias1 = b1[h * 32 + 16 + col];
#pragma unroll
        for (int reg = 0; reg < 4; reg++) {
            int r = quad * 4 + reg;
            float o0 = c0[reg] + bias0;
            float o1 = c1[reg] + bias1;
            o0 = (o0 > 0.f) ? o0 : (__expf(o0) - 1.f);
            o1 = (o1 > 0.f) ? o1 : (__expf(o1) - 1.f);
            H[tl][r * HSTRIDE + h * 32 + col]      = f2bf(o0);
            H[tl][r * HSTRIDE + h * 32 + 16 + col] = f2bf(o1);
        }
    }
    __syncthreads();

    floatx4 acc[4];
#pragma unroll
    for (int c = 0; c < 4; c++) acc[c] = (floatx4){0.f, 0.f, 0.f, 0.f};
    const bf16x8* pb = (const bf16x8*)W2p;
#pragma unroll
    for (int kb = 0; kb < 10; kb++) {
        bf16x8 a = *(const bf16x8*)&H[tl][(lane & 15) * HSTRIDE + kb * 32 + quad * 8];
#pragma unroll
        for (int c = 0; c < 4; c++) {
            bf16x8 b = pb[(kb * 8 + (4 * w + c)) * 64 + lane];
            acc[c] = __builtin_amdgcn_mfma_f32_16x16x32_bf16(a, b, acc[c], 0, 0, 0);
        }
    }
    float asv[4], adv[4];
#pragma unroll
    for (int c = 0; c < 4; c++) {
        asv[c] = a_src[(4 * w + c) * 16 + col];
        adv[c] = a_dst[(4 * w + c) * 16 + col];
    }
#pragma unroll
    for (int reg = 0; reg < 4; reg++) {
        int row = row0 + quad * 4 + reg;
        float vs = 0.f, vd = 0.f;
#pragma unroll
        for (int c = 0; c < 4; c++) {
            float v = acc[c][reg];
            xw2h[(size_t)row * C2 + (4 * w + c) * 16 + col] = (f16)v;
            vs += v * asv[c];
            vd += v * adv[c];
        }
#pragma unroll
        for (int off = 8; off >= 1; off >>= 1) {
            vs += __shfl_xor(vs, off);
            vd += __shfl_xor(vd, off);
        }
        if (col == 0) { redS[tl][w][quad * 4 + reg] = vs; redD[tl][w][quad * 4 + reg] = vd; }
    }
    __syncthreads();
    if (w == 0) {
        if (lane < 16)
            s_src2[row0 + lane] = redS[tl][0][lane] + redS[tl][1][lane];
        else if (lane < 32)
            s_dst2[row0 + lane - 16] = redD[tl][0][lane - 16] + redD[tl][1][lane - 16];
    }
}

// ---------------------------------------------------------------------------
// Fused layer-2 aggregation + fc: one 16-node tile, 256 threads, 4 nodes/wave.
// Pooling via tile-local max + atomicMax; pooled fc is a SEPARATE kernel
// (round-14's last-block fusion serialized 100 device-scope atomic rounds
// through one CU -> 324 us tail. Never again.)
// ---------------------------------------------------------------------------
__global__ __launch_bounds__(256) void agg2fc_kernel(
        const f16* __restrict__ xw2h, const float* __restrict__ s_src2,
        const float* __restrict__ s_dst2, const int* __restrict__ deg_arr,
        const int* __restrict__ csr_src, const float* __restrict__ b2,
        const f16* __restrict__ FCp, const float* __restrict__ fcb,
        float* __restrict__ out, int* __restrict__ pooledi) {
    __shared__ __align__(8) int2 shE[4][64];          // 2 KB
    __shared__ __align__(16) f16 X[16 * X2STRIDE];    // 4.25 KB
    int wslot = threadIdx.x >> 6;
    int lane = threadIdx.x & 63;
    int row0 = blockIdx.x * 16;          // 1250 blocks
    int2* E = shE[wslot];

    // ---- phase 1: 4 nodes per wave ----
#pragma unroll
    for (int rep = 0; rep < 4; rep++) {
        int r = wslot * 4 + rep;
        int n = row0 + r;
        int beg = n * CAP, deg = deg_arr[n];
        float sd = s_dst2[n];
        float l = 0.f, a0 = 0.f, a1 = 0.f;

        for (int c0 = 0; c0 < deg; c0 += 64) {
            int dc = min(deg - c0, 64);
            bool act = lane < dc;
            int s_e = csr_src[beg + c0 + min(lane, dc - 1)];
            float e = s_src2[s_e] + sd;
            e = (e >= 0.f) ? e : 0.2f * e;
            float p = act ? __expf(e) : 0.f;
            float su = p;
#pragma unroll
            for (int off = 32; off >= 1; off >>= 1) su += __shfl_xor(su, off);
            l += su;

            E[lane] = make_int2(s_e, __float_as_int(p));
            asm volatile("s_waitcnt lgkmcnt(0)" ::: "memory");

            int dcr = (dc + 3) & ~3;                  // pad rows have p=0
            for (int i = 0; i < dcr; i += 4) {
                int2 e0 = E[i + 0], e1 = E[i + 1], e2 = E[i + 2], e3 = E[i + 3];
                f16x2 v0 = *(const f16x2*)(xw2h + (size_t)e0.x * C2 + 2 * lane);
                f16x2 v1 = *(const f16x2*)(xw2h + (size_t)e1.x * C2 + 2 * lane);
                f16x2 v2 = *(const f16x2*)(xw2h + (size_t)e2.x * C2 + 2 * lane);
                f16x2 v3 = *(const f16x2*)(xw2h + (size_t)e3.x * C2 + 2 * lane);
                float p0 = __int_as_float(e0.y), p1 = __int_as_float(e1.y);
                float p2 = __int_as_float(e2.y), p3 = __int_as_float(e3.y);
                a0 += p0 * (float)v0.x + p1 * (float)v1.x + p2 * (float)v2.x + p3 * (float)v3.x;
                a1 += p0 * (float)v0.y + p1 * (float)v1.y + p2 * (float)v2.y + p3 * (float)v3.y;
            }
            asm volatile("s_waitcnt lgkmcnt(0)" ::: "memory");
        }

        float linv = 1.f / fmaxf(l, 1e-16f);
        float2 bb = *(const float2*)(b2 + 2 * lane);
        f16x2 o;
        o.x = (f16)fmaxf(a0 * linv + bb.x, 0.f);
        o.y = (f16)fmaxf(a1 * linv + bb.y, 0.f);
        *(f16x2*)&X[r * X2STRIDE + 2 * lane] = o;
    }
    __syncthreads();

    // ---- phase 2a: fc MFMA — wave w covers ct = 2w, 2w+1 ----
    int quad = lane >> 4, col = lane & 15;
    floatx4 acc[2];
    acc[0] = (floatx4){0.f, 0.f, 0.f, 0.f};
    acc[1] = (floatx4){0.f, 0.f, 0.f, 0.f};
    const f16x8* pb = (const f16x8*)FCp;
#pragma unroll
    for (int kb = 0; kb < 4; kb++) {
        f16x8 a = *(const f16x8*)&X[(lane & 15) * X2STRIDE + kb * 32 + quad * 8];
#pragma unroll
        for (int c = 0; c < 2; c++) {
            int ct = wslot * 2 + c;
            f16x8 b = pb[(kb * 8 + ct) * 64 + lane];
            acc[c] = __builtin_amdgcn_mfma_f32_16x16x32_f16(a, b, acc[c], 0, 0, 0);
        }
    }
#pragma unroll
    for (int c = 0; c < 2; c++) {
        int ct = wslot * 2 + c;
        float bias = fcb[ct * 16 + col];
#pragma unroll
        for (int reg = 0; reg < 4; reg++) {
            int row = row0 + quad * 4 + reg;
            out[(size_t)row * C2 + ct * 16 + col] = fmaxf(acc[c][reg] + bias, 0.f);
        }
    }

    // ---- phase 2b: tile-local pooling max + atomicMax (threads 0..127) ----
    if (threadIdx.x < C2) {
        int c = threadIdx.x;
        int gA = row0 / PER;
        int gB = (row0 + 15) / PER;
        float mA = 0.f, mB = 0.f;        // x2 >= 0, 0 is identity
#pragma unroll
        for (int r = 0; r < 16; r++) {
            float v = (float)X[r * X2STRIDE + c];
            if ((row0 + r) / PER == gA) mA = fmaxf(mA, v);
            else                        mB = fmaxf(mB, v);
        }
        atomicMax(&pooledi[gA * C2 + c], __float_as_int(mA));
        if (gB != gA) atomicMax(&pooledi[gB * C2 + c], __float_as_int(mB));
    }
}

// ---------------------------------------------------------------------------
// Final pooled fc: relu(pooled @ fc_w + fc_b)  — 100 parallel blocks
// ---------------------------------------------------------------------------
__global__ void poolfc_kernel(const int* __restrict__ pooledi, const float* __restrict__ fcw,
                              const float* __restrict__ fcb, float* __restrict__ outp) {
    __shared__ float mx[C2];
    int g = blockIdx.x, t = threadIdx.x;   // 128
    mx[t] = __int_as_float(pooledi[g * C2 + t]);
    __syncthreads();
    float acc = 0.f;
    for (int k = 0; k < C2; k++) acc += mx[k] * fcw[k * C2 + t];
    outp[g * C2 + t] = fmaxf(acc + fcb[t], 0.f);
}

// ---------------------------------------------------------------------------
extern "C" void kernel_launch(void* const* d_in, const int* in_sizes, int n_in,
                              void* d_out, int out_size, void* d_ws, size_t ws_size,
                              hipStream_t stream) {
    const float* feats = (const float*)d_in[0];
    const int*   ei    = (const int*)d_in[1];
    const float* W1  = (const float*)d_in[4];
    const float* a1s = (const float*)d_in[5];
    const float* a1d = (const float*)d_in[6];
    const float* b1  = (const float*)d_in[7];
    const float* W2  = (const float*)d_in[8];
    const float* a2s = (const float*)d_in[9];
    const float* a2d = (const float*)d_in[10];
    const float* b2  = (const float*)d_in[11];
    const float* fcw = (const float*)d_in[12];
    const float* fcb = (const float*)d_in[13];

    float* out_main = (float*)d_out;                        // [20000,128]
    float* out_pool = (float*)d_out + (size_t)N_NODES * C2; // [100,128]

    char* p = (char*)d_ws;
    auto alloc = [&](size_t bytes) {
        char* r = p;
        p += (bytes + 255) & ~(size_t)255;
        return r;
    };
    unsigned short* gn   = (unsigned short*)alloc(sizeof(short) * (size_t)N_NODES * C1);
    unsigned short* W2p  = (unsigned short*)alloc(sizeof(short) * C1 * C2);
    unsigned short* W1p  = (unsigned short*)alloc(sizeof(short) * HEADS * F_IN * F_IN);
    f16*   FCp     = (f16*)alloc(sizeof(f16) * C2 * C2);
    f16*   feats16 = (f16*)alloc(sizeof(f16) * (size_t)N_NODES * F_IN);
    f16*   xw2h    = (f16*)alloc(sizeof(f16) * (size_t)N_NODES * C2);
    float* s1s    = (float*)alloc(sizeof(float) * N_NODES * HEADS);
    float* s1d    = (float*)alloc(sizeof(float) * N_NODES * HEADS);
    float* s2s    = (float*)alloc(sizeof(float) * N_NODES);
    float* s2d    = (float*)alloc(sizeof(float) * N_NODES);
    // zero region: cursor + pooledi in one memset
    const int NZ = N_NODES + NB * C2;
    int* zeros   = (int*)alloc(sizeof(int) * NZ);
    int* cursor  = zeros;
    int* pooledi = zeros + N_NODES;
    int* csr_src = (int*)alloc(sizeof(int) * N_NODES * CAP); // bucket CSR

    hipMemsetAsync(zeros, 0, sizeof(int) * NZ, stream);

    mega_prep_kernel<<<SCAT_BLOCKS + SCORE_BLOCKS + W2P_BLOCKS + W1P_BLOCKS + FCP_BLOCKS + F16_BLOCKS,
                       256, 0, stream>>>(
        ei, cursor, csr_src, feats, feats16, W1, W1p, W2, W2p, fcw, FCp,
        a1s, a1d, s1s, s1d);

    aggg1_kernel<<<5000, 256, 0, stream>>>(feats16, s1s, s1d, cursor, csr_src, gn);
    h1gemm2_kernel<<<625, 256, 0, stream>>>(gn, W1p, b1, W2p, a2s, a2d, xw2h, s2s, s2d);
    agg2fc_kernel<<<1250, 256, 0, stream>>>(xw2h, s2s, s2d, cursor, csr_src, b2,
                                            FCp, fcb, out_main, pooledi);
    poolfc_kernel<<<NB, C2, 0, stream>>>(pooledi, fcw, fcb, out_pool);
}